// Round 15
// baseline (131.624 us; speedup 1.0000x reference)
//
#include <hip/hip_runtime.h>
#include <math.h>

#define BLK  256
#define DD   128
#define NN   15
#define NL   16
#define OC   16
#define OSTR 20      // LDS patch row stride (f32)
#define GAPTHR 1e-3f

typedef __attribute__((ext_vector_type(8))) short short8v;
typedef __attribute__((ext_vector_type(4))) float f32x4;
typedef union { unsigned u[4]; short8v s; } fragu;

__device__ inline unsigned bf16_rne_u(float f) {
    unsigned u = __float_as_uint(f);
    return (u + 0x7FFFu + ((u >> 16) & 1u)) >> 16;
}
__device__ inline unsigned cvt_pk_bf16(float a, float b) {  // low16 = a (HW RNE)
    unsigned r;
    asm volatile("v_cvt_pk_bf16_f32 %0, %1, %2" : "=v"(r) : "v"(a), "v"(b));
    return r;
}
// split 8 f32 into bf16 hi + bf16 residual fragments
__device__ inline void split8(const float v[8], short8v& hi, short8v& lo) {
    fragu H, L;
    #pragma unroll
    for (int p = 0; p < 4; ++p) {
        const float a = v[2*p], b = v[2*p+1];
        const unsigned h = cvt_pk_bf16(a, b);
        H.u[p] = h;
        const float ra = a - __uint_as_float(h << 16);
        const float rb = b - __uint_as_float(h & 0xFFFF0000u);
        L.u[p] = cvt_pk_bf16(ra, rb);
    }
    hi = H.s; lo = L.s;
}

// ---- prep: weights -> MFMA-fragment-native bf16 layouts in d_ws ----
__global__ __launch_bounds__(256)
void dts_prep(const float* __restrict__ Wn, const float* __restrict__ Wl,
              unsigned short* __restrict__ wlB,
              unsigned short* __restrict__ wnHi, unsigned short* __restrict__ wnLo)
{
    const int id = blockIdx.x * 256 + threadIdx.x;
    if (id < 32768) {
        const int j = id & 7, n = (id >> 3) & 15, g = (id >> 7) & 3,
                  c = (id >> 9) & 3, leaf = id >> 11;
        const int k = c * 32 + g * 8 + j;
        wlB[id] = (unsigned short)bf16_rne_u(Wl[((size_t)leaf * DD + k) * OC + n]);
    } else if (id < 32768 + 2048) {
        const int id2 = id - 32768;
        const int j = id2 & 7, n = (id2 >> 3) & 15, g = (id2 >> 7) & 3, c = id2 >> 9;
        const int k = c * 32 + g * 8 + j;
        const float v = (n < NN) ? Wn[k * NN + n] : 0.f;   // Wn is [D][NN]
        const unsigned hb = bf16_rne_u(v);
        wnHi[id2] = (unsigned short)hb;
        wnLo[id2] = (unsigned short)bf16_rne_u(v - __uint_as_float(hb << 16));
    }
}

__global__ __launch_bounds__(BLK, 4)
void dts_fused15(const float* __restrict__ x, const float* __restrict__ Wn,
                 const float* __restrict__ bn, const float* __restrict__ bl,
                 const unsigned short* __restrict__ wlB,
                 const unsigned short* __restrict__ wnHi,
                 const unsigned short* __restrict__ wnLo,
                 float* __restrict__ out, int B)
{
    __shared__ __align__(16) float sXch[BLK * OSTR];   // per-wave patch: logits, then out
    __shared__ float sBn[NN];
    __shared__ __align__(16) float sBl[NL * OC];
    __shared__ unsigned char sLeaf[BLK];

    const int t    = threadIdx.x;
    const int wv   = t >> 6;
    const int lane = t & 63;
    const int lo16 = t & 15;
    const int grp  = (t >> 4) & 3;
    const int rowBase = blockIdx.x * BLK;   // B = grid*256 exactly

    // base pointer for this lane's fragment rows (i-th row-tile at +i*16*DD)
    const float* xb = x + (size_t)(rowBase + wv * 64 + lo16) * DD + grp * 8;

    // ---- phase-1 x prefetch, chunk 0, issued before anything else ----
    float4 XA0, XA1, XA2, XA3, XA4, XA5, XA6, XA7;
    float4 XB0, XB1, XB2, XB3, XB4, XB5, XB6, XB7;
    #define XLOAD(S, c) { \
        S##0 = *(const float4*)(xb + 0 * 16 * DD + (c) * 32); \
        S##1 = *(const float4*)(xb + 0 * 16 * DD + (c) * 32 + 4); \
        S##2 = *(const float4*)(xb + 1 * 16 * DD + (c) * 32); \
        S##3 = *(const float4*)(xb + 1 * 16 * DD + (c) * 32 + 4); \
        S##4 = *(const float4*)(xb + 2 * 16 * DD + (c) * 32); \
        S##5 = *(const float4*)(xb + 2 * 16 * DD + (c) * 32 + 4); \
        S##6 = *(const float4*)(xb + 3 * 16 * DD + (c) * 32); \
        S##7 = *(const float4*)(xb + 3 * 16 * DD + (c) * 32 + 4); }
    XLOAD(XA, 0)

    if (t < NN) sBn[t] = bn[t];
    for (int i = t; i < NL * OC; i += BLK) sBl[i] = bl[i];
    __syncthreads();       // the ONLY block barrier

    // ===== phase 1: split-bf16 MFMA, depth-1 prefetched chunks =====
    short8v ah[4][4];      // [c][i], static indices
    f32x4 accn[4];
    #pragma unroll
    for (int i = 0; i < 4; ++i) accn[i] = (f32x4){0.f, 0.f, 0.f, 0.f};

    #define XONE(S0, S1, c, i) { \
        float av[8]; \
        av[0]=S0.x; av[1]=S0.y; av[2]=S0.z; av[3]=S0.w; \
        av[4]=S1.x; av[5]=S1.y; av[6]=S1.z; av[7]=S1.w; \
        short8v hi_, lo_; split8(av, hi_, lo_); ah[c][i] = hi_; \
        accn[i] = __builtin_amdgcn_mfma_f32_16x16x32_bf16(hi_, bh_, accn[i], 0, 0, 0); \
        accn[i] = __builtin_amdgcn_mfma_f32_16x16x32_bf16(lo_, bh_, accn[i], 0, 0, 0); \
        accn[i] = __builtin_amdgcn_mfma_f32_16x16x32_bf16(hi_, bw_, accn[i], 0, 0, 0); }
    #define XCHUNK(S, c) { \
        const short8v bh_ = *(const short8v*)&wnHi[((c) * 64 + lane) * 8]; \
        const short8v bw_ = *(const short8v*)&wnLo[((c) * 64 + lane) * 8]; \
        XONE(S##0, S##1, c, 0) XONE(S##2, S##3, c, 1) \
        XONE(S##4, S##5, c, 2) XONE(S##6, S##7, c, 3) }

    XLOAD(XB, 1)                         // prefetch chunk 1
    XCHUNK(XA, 0)                        // compute chunk 0
    __builtin_amdgcn_sched_barrier(0);
    XLOAD(XA, 2)
    XCHUNK(XB, 1)
    __builtin_amdgcn_sched_barrier(0);
    XLOAD(XB, 3)
    XCHUNK(XA, 2)
    __builtin_amdgcn_sched_barrier(0);
    XCHUNK(XB, 3)
    __builtin_amdgcn_sched_barrier(0);
    #undef XCHUNK
    #undef XONE
    #undef XLOAD

    // ---- in-wave transpose via private LDS patch ----
    {
        float* patch = &sXch[wv * 64 * OSTR];
        #pragma unroll
        for (int i = 0; i < 4; ++i)
            #pragma unroll
            for (int j = 0; j < 4; ++j)
                patch[(i * 16 + grp * 4 + j) * OSTR + lo16] = accn[i][j];
    }
    asm volatile("s_waitcnt lgkmcnt(0)" ::: "memory");
    __builtin_amdgcn_sched_barrier(0);

    float nl[16];
    {
        const float4* np = (const float4*)&sXch[t * OSTR];
        const float4 n0 = np[0], n1 = np[1], n2 = np[2], n3 = np[3];
        nl[0]=n0.x; nl[1]=n0.y; nl[2]=n0.z;  nl[3]=n0.w;
        nl[4]=n1.x; nl[5]=n1.y; nl[6]=n1.z;  nl[7]=n1.w;
        nl[8]=n2.x; nl[9]=n2.y; nl[10]=n2.z; nl[11]=n2.w;
        nl[12]=n3.x; nl[13]=n3.y; nl[14]=n3.z;
    }
    #pragma unroll
    for (int n = 0; n < NN; ++n) nl[n] += sBn[n];

    // ---- tree expand + top-2 argmax ----
    float L2a[4], L3a[8], L4a[16];
    #define EXPAND(src) { \
        float p = src[0], m = -src[0]; \
        L2a[0] = p + src[1]; L2a[1] = p - src[1]; \
        L2a[2] = m + src[2]; L2a[3] = m - src[2]; \
        _Pragma("unroll") \
        for (int i = 0; i < 4; ++i) { L3a[2*i] = L2a[i] + src[3+i]; L3a[2*i+1] = L2a[i] - src[3+i]; } \
        _Pragma("unroll") \
        for (int i = 0; i < 8; ++i) { L4a[2*i] = L3a[i] + src[7+i]; L4a[2*i+1] = L3a[i] - src[7+i]; } }
    EXPAND(nl)
    int best = 0; float bv = L4a[0], sv = -1e30f;
    #pragma unroll
    for (int l = 1; l < NL; ++l) {
        if (L4a[l] > bv) { sv = bv; bv = L4a[l]; best = l; }
        else if (L4a[l] > sv) sv = L4a[l];
    }

    // rare exact f32 recompute for near-ties (argmax safety)
    if (bv - sv < GAPTHR) {
        float e[NN];
        #pragma unroll
        for (int n = 0; n < NN; ++n) e[n] = 0.f;
        const float* xrow = x + (size_t)(rowBase + t) * DD;
        for (int d = 0; d < DD; ++d) {
            const float xd = xrow[d];
            const float* wr = Wn + d * NN;
            #pragma unroll
            for (int n = 0; n < NN; ++n) e[n] = fmaf(xd, wr[n], e[n]);
        }
        #pragma unroll
        for (int n = 0; n < NN; ++n) e[n] += sBn[n];
        EXPAND(e)
        best = 0; bv = L4a[0];
        #pragma unroll
        for (int l = 1; l < NL; ++l) if (L4a[l] > bv) { bv = L4a[l]; best = l; }
    }
    #undef EXPAND

    // ---- share leaves within wave ----
    sLeaf[t] = (unsigned char)best;
    asm volatile("s_waitcnt lgkmcnt(0)" ::: "memory");
    __builtin_amdgcn_sched_barrier(0);

    unsigned lfp[4];       // packed leaves of rows (rt*16 + grp*4 + 0..3)
    #pragma unroll
    for (int rt = 0; rt < 4; ++rt)
        lfp[rt] = *(const unsigned*)&sLeaf[wv * 64 + rt * 16 + grp * 4];

    // ===== phase 3: all-leaf GEMM, depth-1 prefetched B-frags, cndmask select =====
    f32x4 keep[4];
    #pragma unroll
    for (int rt = 0; rt < 4; ++rt) keep[rt] = (f32x4){0.f, 0.f, 0.f, 0.f};

    short8v bfA0, bfA1, bfA2, bfA3, bfB0, bfB1, bfB2, bfB3;
    const int fo = lane * 8;
    bfA0 = *(const short8v*)&wlB[fo];
    bfA1 = *(const short8v*)&wlB[ 512 + fo];
    bfA2 = *(const short8v*)&wlB[1024 + fo];
    bfA3 = *(const short8v*)&wlB[1536 + fo];

    #define DOLEAF(nt, F0, F1, F2, F3) { \
        f32x4 acc[4]; \
        _Pragma("unroll") \
        for (int rt = 0; rt < 4; ++rt) acc[rt] = (f32x4){0.f, 0.f, 0.f, 0.f}; \
        _Pragma("unroll") \
        for (int rt = 0; rt < 4; ++rt) { \
            acc[rt] = __builtin_amdgcn_mfma_f32_16x16x32_bf16(ah[0][rt], F0, acc[rt], 0, 0, 0); \
            acc[rt] = __builtin_amdgcn_mfma_f32_16x16x32_bf16(ah[1][rt], F1, acc[rt], 0, 0, 0); \
            acc[rt] = __builtin_amdgcn_mfma_f32_16x16x32_bf16(ah[2][rt], F2, acc[rt], 0, 0, 0); \
            acc[rt] = __builtin_amdgcn_mfma_f32_16x16x32_bf16(ah[3][rt], F3, acc[rt], 0, 0, 0); \
        } \
        _Pragma("unroll") \
        for (int rt = 0; rt < 4; ++rt) \
            _Pragma("unroll") \
            for (int j = 0; j < 4; ++j) \
                keep[rt][j] = (((lfp[rt] >> (8 * j)) & 0xFFu) == (unsigned)(nt)) \
                            ? acc[rt][j] : keep[rt][j]; }

    #pragma unroll 1
    for (int nt = 0; nt < NL; nt += 2) {
        const int nB = nt + 1;
        bfB0 = *(const short8v*)&wlB[nB * 2048 +        fo];
        bfB1 = *(const short8v*)&wlB[nB * 2048 +  512 + fo];
        bfB2 = *(const short8v*)&wlB[nB * 2048 + 1024 + fo];
        bfB3 = *(const short8v*)&wlB[nB * 2048 + 1536 + fo];
        DOLEAF(nt, bfA0, bfA1, bfA2, bfA3)
        const int nA = (nt + 2 < NL) ? nt + 2 : 0;   // harmless dummy on last iter
        bfA0 = *(const short8v*)&wlB[nA * 2048 +        fo];
        bfA1 = *(const short8v*)&wlB[nA * 2048 +  512 + fo];
        bfA2 = *(const short8v*)&wlB[nA * 2048 + 1024 + fo];
        bfA3 = *(const short8v*)&wlB[nA * 2048 + 1536 + fo];
        DOLEAF(nB, bfB0, bfB1, bfB2, bfB3)
    }
    #undef DOLEAF

    // ===== epilogue: bias, un-permute via patch, coalesced store =====
    {
        float* patch = &sXch[wv * 64 * OSTR];
        #pragma unroll
        for (int rt = 0; rt < 4; ++rt)
            #pragma unroll
            for (int j = 0; j < 4; ++j) {
                const int lf = (lfp[rt] >> (8 * j)) & 0xFF;
                patch[(rt * 16 + grp * 4 + j) * OSTR + lo16] =
                    keep[rt][j] + sBl[lf * OC + lo16];
            }
    }
    asm volatile("s_waitcnt lgkmcnt(0)" ::: "memory");
    __builtin_amdgcn_sched_barrier(0);
    {
        const float* so = &sXch[t * OSTR];
        const float4 m0 = *(const float4*)(so);
        const float4 m1 = *(const float4*)(so + 4);
        const float4 s0 = *(const float4*)(so + 8);
        const float4 s1 = *(const float4*)(so + 12);

        const size_t ob = (size_t)(rowBase + t) * 8;
        *reinterpret_cast<float4*>(&out[ob])     = m0;
        *reinterpret_cast<float4*>(&out[ob + 4]) = m1;

        // log_std = -1.5 + 3.5*tanh(v); tanh = 1 - 2/(e^{2v}+1)
        float4 r0, r1;
        #define SQ(v) (-1.5f + 3.5f * (1.f - 2.f / (__expf(2.f * (v)) + 1.f)))
        r0.x = SQ(s0.x); r0.y = SQ(s0.y); r0.z = SQ(s0.z); r0.w = SQ(s0.w);
        r1.x = SQ(s1.x); r1.y = SQ(s1.y); r1.z = SQ(s1.z); r1.w = SQ(s1.w);
        #undef SQ
        const size_t ob2 = (size_t)B * 8 + ob;
        *reinterpret_cast<float4*>(&out[ob2])     = r0;
        *reinterpret_cast<float4*>(&out[ob2 + 4]) = r1;
    }
}

extern "C" void kernel_launch(void* const* d_in, const int* in_sizes, int n_in,
                              void* d_out, int out_size, void* d_ws, size_t ws_size,
                              hipStream_t stream)
{
    const float* x  = (const float*)d_in[0];
    const float* Wn = (const float*)d_in[1];
    const float* bn = (const float*)d_in[2];
    const float* Wl = (const float*)d_in[3];
    const float* bl = (const float*)d_in[4];
    float* out = (float*)d_out;

    unsigned short* wlB  = (unsigned short*)d_ws;          // 32768 bf16
    unsigned short* wnHi = wlB + 32768;                    //  2048 bf16
    unsigned short* wnLo = wnHi + 2048;                    //  2048 bf16

    const int B = in_sizes[0] / DD;              // 262144
    const int blocks = (B + BLK - 1) / BLK;      // 1024

    hipLaunchKernelGGL(dts_prep, dim3(136), dim3(256), 0, stream, Wn, Wl, wlB, wnHi, wnLo);
    hipLaunchKernelGGL(dts_fused15, dim3(blocks), dim3(BLK), 0, stream,
                       x, Wn, bn, bl, wlB, wnHi, wnLo, out, B);
}

// Round 16
// 80.356 us; speedup vs baseline: 1.6380x; 1.6380x over previous
//
#include <hip/hip_runtime.h>
#include <math.h>

#define BLK  256
#define RPB  128     // rows per block
#define RPW  32      // rows per wave
#define DD   128
#define NN   15
#define NL   16
#define OC   16
#define OSTR 20      // LDS patch row stride (f32)
#define GAPTHR 1e-3f

typedef __attribute__((ext_vector_type(8))) short short8v;
typedef __attribute__((ext_vector_type(4))) float f32x4;
typedef union { unsigned u[4]; short8v s; } fragu;

__device__ inline unsigned bf16_rne_u(float f) {
    unsigned u = __float_as_uint(f);
    return (u + 0x7FFFu + ((u >> 16) & 1u)) >> 16;
}
__device__ inline unsigned cvt_pk_bf16(float a, float b) {  // low16 = a (HW RNE)
    unsigned r;
    asm volatile("v_cvt_pk_bf16_f32 %0, %1, %2" : "=v"(r) : "v"(a), "v"(b));
    return r;
}
// split 8 f32 into bf16 hi + bf16 residual fragments
__device__ inline void split8(const float v[8], short8v& hi, short8v& lo) {
    fragu H, L;
    #pragma unroll
    for (int p = 0; p < 4; ++p) {
        const float a = v[2*p], b = v[2*p+1];
        const unsigned h = cvt_pk_bf16(a, b);
        H.u[p] = h;
        const float ra = a - __uint_as_float(h << 16);
        const float rb = b - __uint_as_float(h & 0xFFFF0000u);
        L.u[p] = cvt_pk_bf16(ra, rb);
    }
    hi = H.s; lo = L.s;
}

// ---- prep: weights -> MFMA-fragment-native bf16 layouts in d_ws ----
__global__ __launch_bounds__(256)
void dts_prep(const float* __restrict__ Wn, const float* __restrict__ Wl,
              unsigned short* __restrict__ wlB,
              unsigned short* __restrict__ wnHi, unsigned short* __restrict__ wnLo)
{
    const int id = blockIdx.x * 256 + threadIdx.x;
    if (id < 32768) {
        const int j = id & 7, n = (id >> 3) & 15, g = (id >> 7) & 3,
                  c = (id >> 9) & 3, leaf = id >> 11;
        const int k = c * 32 + g * 8 + j;
        wlB[id] = (unsigned short)bf16_rne_u(Wl[((size_t)leaf * DD + k) * OC + n]);
    } else if (id < 32768 + 2048) {
        const int id2 = id - 32768;
        const int j = id2 & 7, n = (id2 >> 3) & 15, g = (id2 >> 7) & 3, c = id2 >> 9;
        const int k = c * 32 + g * 8 + j;
        const float v = (n < NN) ? Wn[k * NN + n] : 0.f;   // Wn is [D][NN]
        const unsigned hb = bf16_rne_u(v);
        wnHi[id2] = (unsigned short)hb;
        wnLo[id2] = (unsigned short)bf16_rne_u(v - __uint_as_float(hb << 16));
    }
}

__global__ __launch_bounds__(BLK, 8)
void dts_fused16(const float* __restrict__ x, const float* __restrict__ Wn,
                 const float* __restrict__ bn, const float* __restrict__ bl,
                 const unsigned short* __restrict__ wlB,
                 const unsigned short* __restrict__ wnHi,
                 const unsigned short* __restrict__ wnLo,
                 float* __restrict__ out, int B)
{
    __shared__ __align__(16) float sXch[RPB * OSTR];   // 10240B: logits, then out
    __shared__ float sBn[NN];
    __shared__ __align__(16) float sBl[NL * OC];
    __shared__ unsigned char sLeaf[RPB];

    const int t    = threadIdx.x;
    const int wv   = t >> 6;
    const int lane = t & 63;
    const int lo16 = t & 15;
    const int grp  = (t >> 4) & 3;
    const int rowBase = blockIdx.x * RPB;   // B = grid*128 exactly

    if (t < NN) sBn[t] = bn[t];
    for (int i = t; i < NL * OC; i += BLK) sBl[i] = bl[i];
    __syncthreads();                        // block barrier 1

    // ===== phase 1: node logits via split-bf16 MFMA (2 row-tiles/wave) =====
    const int waveRow0 = rowBase + wv * RPW;
    short8v ah[4][2];      // [c][i], static indices
    f32x4 accn[2];
    #pragma unroll
    for (int i = 0; i < 2; ++i) accn[i] = (f32x4){0.f, 0.f, 0.f, 0.f};

    #pragma unroll
    for (int c = 0; c < 4; ++c) {
        const short8v bh = *(const short8v*)&wnHi[(c * 64 + lane) * 8];  // coalesced
        const short8v bw = *(const short8v*)&wnLo[(c * 64 + lane) * 8];
        #pragma unroll
        for (int i = 0; i < 2; ++i) {
            const float* ap = x + (size_t)(waveRow0 + i * 16 + lo16) * DD + c * 32 + grp * 8;
            const float4 a0 = *(const float4*)ap;
            const float4 a1 = *(const float4*)(ap + 4);
            float av[8];
            av[0]=a0.x; av[1]=a0.y; av[2]=a0.z; av[3]=a0.w;
            av[4]=a1.x; av[5]=a1.y; av[6]=a1.z; av[7]=a1.w;
            short8v hi, lo;
            split8(av, hi, lo);
            ah[c][i] = hi;
            accn[i] = __builtin_amdgcn_mfma_f32_16x16x32_bf16(hi, bh, accn[i], 0, 0, 0);
            accn[i] = __builtin_amdgcn_mfma_f32_16x16x32_bf16(lo, bh, accn[i], 0, 0, 0);
            accn[i] = __builtin_amdgcn_mfma_f32_16x16x32_bf16(hi, bw, accn[i], 0, 0, 0);
        }
        __builtin_amdgcn_sched_barrier(0);   // keep f32 transients chunk-local (no spill)
    }

    // ---- in-wave transpose via private LDS patch (rows wv*32 .. +31) ----
    {
        float* patch = &sXch[wv * RPW * OSTR];
        #pragma unroll
        for (int i = 0; i < 2; ++i)
            #pragma unroll
            for (int j = 0; j < 4; ++j)
                patch[(i * 16 + grp * 4 + j) * OSTR + lo16] = accn[i][j];
    }
    asm volatile("s_waitcnt lgkmcnt(0)" ::: "memory");
    __builtin_amdgcn_sched_barrier(0);

    // ---- argmax: lanes 0..31 each own one row (wave-private) ----
    if (lane < RPW) {
        float nl[16];
        {
            const float4* np = (const float4*)&sXch[(wv * RPW + lane) * OSTR];
            const float4 n0 = np[0], n1 = np[1], n2 = np[2], n3 = np[3];
            nl[0]=n0.x; nl[1]=n0.y; nl[2]=n0.z;  nl[3]=n0.w;
            nl[4]=n1.x; nl[5]=n1.y; nl[6]=n1.z;  nl[7]=n1.w;
            nl[8]=n2.x; nl[9]=n2.y; nl[10]=n2.z; nl[11]=n2.w;
            nl[12]=n3.x; nl[13]=n3.y; nl[14]=n3.z;
        }
        #pragma unroll
        for (int n = 0; n < NN; ++n) nl[n] += sBn[n];

        float L2a[4], L3a[8], L4a[16];
        #define EXPAND(src) { \
            float p = src[0], m = -src[0]; \
            L2a[0] = p + src[1]; L2a[1] = p - src[1]; \
            L2a[2] = m + src[2]; L2a[3] = m - src[2]; \
            _Pragma("unroll") \
            for (int i = 0; i < 4; ++i) { L3a[2*i] = L2a[i] + src[3+i]; L3a[2*i+1] = L2a[i] - src[3+i]; } \
            _Pragma("unroll") \
            for (int i = 0; i < 8; ++i) { L4a[2*i] = L3a[i] + src[7+i]; L4a[2*i+1] = L3a[i] - src[7+i]; } }
        EXPAND(nl)
        int best = 0; float bv = L4a[0], sv = -1e30f;
        #pragma unroll
        for (int l = 1; l < NL; ++l) {
            if (L4a[l] > bv) { sv = bv; bv = L4a[l]; best = l; }
            else if (L4a[l] > sv) sv = L4a[l];
        }

        // rare exact f32 recompute for near-ties (argmax safety)
        if (bv - sv < GAPTHR) {
            float e[NN];
            #pragma unroll
            for (int n = 0; n < NN; ++n) e[n] = 0.f;
            const float* xrow = x + (size_t)(waveRow0 + lane) * DD;
            for (int d = 0; d < DD; ++d) {
                const float xd = xrow[d];
                const float* wr = Wn + d * NN;
                #pragma unroll
                for (int n = 0; n < NN; ++n) e[n] = fmaf(xd, wr[n], e[n]);
            }
            #pragma unroll
            for (int n = 0; n < NN; ++n) e[n] += sBn[n];
            EXPAND(e)
            best = 0; bv = L4a[0];
            #pragma unroll
            for (int l = 1; l < NL; ++l) if (L4a[l] > bv) { bv = L4a[l]; best = l; }
        }
        #undef EXPAND

        sLeaf[wv * RPW + lane] = (unsigned char)best;
    }
    asm volatile("s_waitcnt lgkmcnt(0)" ::: "memory");
    __builtin_amdgcn_sched_barrier(0);

    unsigned lfp[2];       // packed leaves of rows (rt*16 + grp*4 + 0..3)
    #pragma unroll
    for (int rt = 0; rt < 2; ++rt)
        lfp[rt] = *(const unsigned*)&sLeaf[wv * RPW + rt * 16 + grp * 4];

    // ===== phase 3: all-leaf GEMM from register A-frags; cndmask select =====
    f32x4 keep[2];
    #pragma unroll
    for (int rt = 0; rt < 2; ++rt) keep[rt] = (f32x4){0.f, 0.f, 0.f, 0.f};

    #pragma unroll 1
    for (int nt = 0; nt < NL; ++nt) {
        short8v bf[4];
        #pragma unroll
        for (int c = 0; c < 4; ++c)
            bf[c] = *(const short8v*)&wlB[nt * 2048 + (c * 64 + lane) * 8];
        f32x4 acc[2];
        #pragma unroll
        for (int rt = 0; rt < 2; ++rt) acc[rt] = (f32x4){0.f, 0.f, 0.f, 0.f};
        #pragma unroll
        for (int c = 0; c < 4; ++c)
            #pragma unroll
            for (int rt = 0; rt < 2; ++rt)
                acc[rt] = __builtin_amdgcn_mfma_f32_16x16x32_bf16(ah[c][rt], bf[c], acc[rt], 0, 0, 0);
        #pragma unroll
        for (int rt = 0; rt < 2; ++rt)
            #pragma unroll
            for (int j = 0; j < 4; ++j)
                keep[rt][j] = (((lfp[rt] >> (8 * j)) & 0xFFu) == (unsigned)nt)
                            ? acc[rt][j] : keep[rt][j];
    }

    // ===== epilogue: bias into patch (wave-private rows) =====
    {
        float* patch = &sXch[wv * RPW * OSTR];
        #pragma unroll
        for (int rt = 0; rt < 2; ++rt)
            #pragma unroll
            for (int j = 0; j < 4; ++j) {
                const int lf = (lfp[rt] >> (8 * j)) & 0xFF;
                patch[(rt * 16 + grp * 4 + j) * OSTR + lo16] =
                    keep[rt][j] + sBl[lf * OC + lo16];
            }
    }
    __syncthreads();                        // block barrier 2 (cross-wave store)

    // ---- coalesced store: thread t -> row t>>1, half (t&1) ----
    {
        const int r = t >> 1;
        const int h = (t & 1) * 4;
        const float* so = &sXch[r * OSTR];
        const float4 mv = *(const float4*)(so + h);
        const float4 sv = *(const float4*)(so + 8 + h);

        const size_t gro = (size_t)(rowBase + r) * 8 + h;
        *reinterpret_cast<float4*>(&out[gro]) = mv;

        // log_std = -1.5 + 3.5*tanh(v); tanh = 1 - 2/(e^{2v}+1)
        float4 rv;
        #define SQ(v) (-1.5f + 3.5f * (1.f - 2.f / (__expf(2.f * (v)) + 1.f)))
        rv.x = SQ(sv.x); rv.y = SQ(sv.y); rv.z = SQ(sv.z); rv.w = SQ(sv.w);
        #undef SQ
        *reinterpret_cast<float4*>(&out[(size_t)B * 8 + gro]) = rv;
    }
}

extern "C" void kernel_launch(void* const* d_in, const int* in_sizes, int n_in,
                              void* d_out, int out_size, void* d_ws, size_t ws_size,
                              hipStream_t stream)
{
    const float* x  = (const float*)d_in[0];
    const float* Wn = (const float*)d_in[1];
    const float* bn = (const float*)d_in[2];
    const float* Wl = (const float*)d_in[3];
    const float* bl = (const float*)d_in[4];
    float* out = (float*)d_out;

    unsigned short* wlB  = (unsigned short*)d_ws;          // 32768 bf16
    unsigned short* wnHi = wlB + 32768;                    //  2048 bf16
    unsigned short* wnLo = wnHi + 2048;                    //  2048 bf16

    const int B = in_sizes[0] / DD;              // 262144
    const int blocks = (B + RPB - 1) / RPB;      // 2048

    hipLaunchKernelGGL(dts_prep, dim3(136), dim3(256), 0, stream, Wn, Wl, wlB, wnHi, wnLo);
    hipLaunchKernelGGL(dts_fused16, dim3(blocks), dim3(BLK), 0, stream,
                       x, Wn, bn, bl, wlB, wnHi, wnLo, out, B);
}

// Round 17
// 60.078 us; speedup vs baseline: 2.1909x; 1.3375x over previous
//
#include <hip/hip_runtime.h>
#include <math.h>

#define BLK  256
#define DD   128
#define NN   15
#define NL   16
#define OC   16
#define OSTR 20      // LDS patch row stride (f32)
#define GAPTHR 1e-3f

typedef __attribute__((ext_vector_type(8))) short short8v;
typedef __attribute__((ext_vector_type(4))) float f32x4;
typedef union { unsigned u[4]; short8v s; } fragu;

__device__ inline unsigned bf16_rne_u(float f) {
    unsigned u = __float_as_uint(f);
    return (u + 0x7FFFu + ((u >> 16) & 1u)) >> 16;
}
__device__ inline unsigned cvt_pk_bf16(float a, float b) {  // low16 = a (HW RNE)
    unsigned r;
    asm volatile("v_cvt_pk_bf16_f32 %0, %1, %2" : "=v"(r) : "v"(a), "v"(b));
    return r;
}
// split 8 f32 into bf16 hi + bf16 residual fragments
__device__ inline void split8(const float v[8], short8v& hi, short8v& lo) {
    fragu H, L;
    #pragma unroll
    for (int p = 0; p < 4; ++p) {
        const float a = v[2*p], b = v[2*p+1];
        const unsigned h = cvt_pk_bf16(a, b);
        H.u[p] = h;
        const float ra = a - __uint_as_float(h << 16);
        const float rb = b - __uint_as_float(h & 0xFFFF0000u);
        L.u[p] = cvt_pk_bf16(ra, rb);
    }
    hi = H.s; lo = L.s;
}

// ---- prep: weights -> MFMA-fragment-native bf16 layouts in d_ws ----
__global__ __launch_bounds__(256)
void dts_prep(const float* __restrict__ Wn, const float* __restrict__ Wl,
              unsigned short* __restrict__ wlB,
              unsigned short* __restrict__ wnHi, unsigned short* __restrict__ wnLo)
{
    const int id = blockIdx.x * 256 + threadIdx.x;
    if (id < 32768) {
        const int j = id & 7, n = (id >> 3) & 15, g = (id >> 7) & 3,
                  c = (id >> 9) & 3, leaf = id >> 11;
        const int k = c * 32 + g * 8 + j;
        wlB[id] = (unsigned short)bf16_rne_u(Wl[((size_t)leaf * DD + k) * OC + n]);
    } else if (id < 32768 + 2048) {
        const int id2 = id - 32768;
        const int j = id2 & 7, n = (id2 >> 3) & 15, g = (id2 >> 7) & 3, c = id2 >> 9;
        const int k = c * 32 + g * 8 + j;
        const float v = (n < NN) ? Wn[k * NN + n] : 0.f;   // Wn is [D][NN]
        const unsigned hb = bf16_rne_u(v);
        wnHi[id2] = (unsigned short)hb;
        wnLo[id2] = (unsigned short)bf16_rne_u(v - __uint_as_float(hb << 16));
    }
}

__global__ __launch_bounds__(BLK, 2)
void dts_fused17(const float* __restrict__ x, const float* __restrict__ Wn,
                 const float* __restrict__ bn, const float* __restrict__ bl,
                 const unsigned short* __restrict__ wlB,
                 const unsigned short* __restrict__ wnHi,
                 const unsigned short* __restrict__ wnLo,
                 float* __restrict__ out, int B)
{
    // 64 KB union: phase-1 logit patch [256][20]f32 -> wlB frags [16][2048]bf16 -> out patch
    __shared__ __align__(16) unsigned short uLDS[32768];
    __shared__ float sBn[NN];
    __shared__ __align__(16) float sBl[NL * OC];
    __shared__ unsigned char sLeaf[BLK];

    float*          patch = (float*)uLDS;
    unsigned short* wlS   = uLDS;

    const int t    = threadIdx.x;
    const int wv   = t >> 6;
    const int lane = t & 63;
    const int lo16 = t & 15;
    const int grp  = (t >> 4) & 3;
    const int rowBase = blockIdx.x * BLK;   // B = grid*256 exactly

    const float* xb = x + (size_t)(rowBase + wv * 64 + lo16) * DD + grp * 8;

    // ---- phase-1 x prefetch chunk 0 ----
    float4 XA0, XA1, XA2, XA3, XA4, XA5, XA6, XA7;
    float4 XB0, XB1, XB2, XB3, XB4, XB5, XB6, XB7;
    #define XLOAD(S, c) { \
        S##0 = *(const float4*)(xb + 0 * 16 * DD + (c) * 32); \
        S##1 = *(const float4*)(xb + 0 * 16 * DD + (c) * 32 + 4); \
        S##2 = *(const float4*)(xb + 1 * 16 * DD + (c) * 32); \
        S##3 = *(const float4*)(xb + 1 * 16 * DD + (c) * 32 + 4); \
        S##4 = *(const float4*)(xb + 2 * 16 * DD + (c) * 32); \
        S##5 = *(const float4*)(xb + 2 * 16 * DD + (c) * 32 + 4); \
        S##6 = *(const float4*)(xb + 3 * 16 * DD + (c) * 32); \
        S##7 = *(const float4*)(xb + 3 * 16 * DD + (c) * 32 + 4); }
    XLOAD(XA, 0)

    if (t < NN) sBn[t] = bn[t];
    for (int i = t; i < NL * OC; i += BLK) sBl[i] = bl[i];
    __syncthreads();                               // barrier 1

    // ===== phase 1: split-bf16 MFMA, depth-1 prefetched chunks =====
    short8v ah[4][4];      // [c][i], static indices
    f32x4 accn[4];
    #pragma unroll
    for (int i = 0; i < 4; ++i) accn[i] = (f32x4){0.f, 0.f, 0.f, 0.f};

    #define XONE(S0, S1, c, i) { \
        float av[8]; \
        av[0]=S0.x; av[1]=S0.y; av[2]=S0.z; av[3]=S0.w; \
        av[4]=S1.x; av[5]=S1.y; av[6]=S1.z; av[7]=S1.w; \
        short8v hi_, lo_; split8(av, hi_, lo_); ah[c][i] = hi_; \
        accn[i] = __builtin_amdgcn_mfma_f32_16x16x32_bf16(hi_, bh_, accn[i], 0, 0, 0); \
        accn[i] = __builtin_amdgcn_mfma_f32_16x16x32_bf16(lo_, bh_, accn[i], 0, 0, 0); \
        accn[i] = __builtin_amdgcn_mfma_f32_16x16x32_bf16(hi_, bw_, accn[i], 0, 0, 0); }
    #define XCHUNK(S, c) { \
        const short8v bh_ = *(const short8v*)&wnHi[((c) * 64 + lane) * 8]; \
        const short8v bw_ = *(const short8v*)&wnLo[((c) * 64 + lane) * 8]; \
        XONE(S##0, S##1, c, 0) XONE(S##2, S##3, c, 1) \
        XONE(S##4, S##5, c, 2) XONE(S##6, S##7, c, 3) }

    XLOAD(XB, 1)
    XCHUNK(XA, 0)
    __builtin_amdgcn_sched_barrier(0);
    XLOAD(XA, 2)
    XCHUNK(XB, 1)
    __builtin_amdgcn_sched_barrier(0);
    XLOAD(XB, 3)
    XCHUNK(XA, 2)
    __builtin_amdgcn_sched_barrier(0);
    XCHUNK(XB, 3)
    __builtin_amdgcn_sched_barrier(0);
    #undef XCHUNK
    #undef XONE
    #undef XLOAD

    // ---- in-wave transpose via private patch rows ----
    {
        float* p_ = &patch[wv * 64 * OSTR];
        #pragma unroll
        for (int i = 0; i < 4; ++i)
            #pragma unroll
            for (int j = 0; j < 4; ++j)
                p_[(i * 16 + grp * 4 + j) * OSTR + lo16] = accn[i][j];
    }
    asm volatile("s_waitcnt lgkmcnt(0)" ::: "memory");
    __builtin_amdgcn_sched_barrier(0);

    float nl[16];
    {
        const float4* np = (const float4*)&patch[t * OSTR];
        const float4 n0 = np[0], n1 = np[1], n2 = np[2], n3 = np[3];
        nl[0]=n0.x; nl[1]=n0.y; nl[2]=n0.z;  nl[3]=n0.w;
        nl[4]=n1.x; nl[5]=n1.y; nl[6]=n1.z;  nl[7]=n1.w;
        nl[8]=n2.x; nl[9]=n2.y; nl[10]=n2.z; nl[11]=n2.w;
        nl[12]=n3.x; nl[13]=n3.y; nl[14]=n3.z;
    }
    #pragma unroll
    for (int n = 0; n < NN; ++n) nl[n] += sBn[n];

    // ---- tree expand + top-2 argmax ----
    float L2a[4], L3a[8], L4a[16];
    #define EXPAND(src) { \
        float p = src[0], m = -src[0]; \
        L2a[0] = p + src[1]; L2a[1] = p - src[1]; \
        L2a[2] = m + src[2]; L2a[3] = m - src[2]; \
        _Pragma("unroll") \
        for (int i = 0; i < 4; ++i) { L3a[2*i] = L2a[i] + src[3+i]; L3a[2*i+1] = L2a[i] - src[3+i]; } \
        _Pragma("unroll") \
        for (int i = 0; i < 8; ++i) { L4a[2*i] = L3a[i] + src[7+i]; L4a[2*i+1] = L3a[i] - src[7+i]; } }
    EXPAND(nl)
    int best = 0; float bv = L4a[0], sv = -1e30f;
    #pragma unroll
    for (int l = 1; l < NL; ++l) {
        if (L4a[l] > bv) { sv = bv; bv = L4a[l]; best = l; }
        else if (L4a[l] > sv) sv = L4a[l];
    }

    // rare exact f32 recompute for near-ties (argmax safety)
    if (bv - sv < GAPTHR) {
        float e[NN];
        #pragma unroll
        for (int n = 0; n < NN; ++n) e[n] = 0.f;
        const float* xrow = x + (size_t)(rowBase + t) * DD;
        for (int d = 0; d < DD; ++d) {
            const float xd = xrow[d];
            const float* wr = Wn + d * NN;
            #pragma unroll
            for (int n = 0; n < NN; ++n) e[n] = fmaf(xd, wr[n], e[n]);
        }
        #pragma unroll
        for (int n = 0; n < NN; ++n) e[n] += sBn[n];
        EXPAND(e)
        best = 0; bv = L4a[0];
        #pragma unroll
        for (int l = 1; l < NL; ++l) if (L4a[l] > bv) { bv = L4a[l]; best = l; }
    }
    #undef EXPAND

    // ---- share leaves within wave ----
    sLeaf[t] = (unsigned char)best;
    asm volatile("s_waitcnt lgkmcnt(0)" ::: "memory");
    __builtin_amdgcn_sched_barrier(0);

    unsigned lfp[4];
    #pragma unroll
    for (int rt = 0; rt < 4; ++rt)
        lfp[rt] = *(const unsigned*)&sLeaf[wv * 64 + rt * 16 + grp * 4];

    // ===== stage wlB (64 KB) into LDS: T14 split (loads early, ds_write after barrier) =====
    uint4 s0,s1,s2,s3,s4,s5,s6,s7,s8,s9,s10,s11,s12,s13,s14,s15;
    {
        const uint4* wsrc = (const uint4*)wlB;     // 4096 uint4
        s0  = wsrc[ 0*BLK + t]; s1  = wsrc[ 1*BLK + t];
        s2  = wsrc[ 2*BLK + t]; s3  = wsrc[ 3*BLK + t];
        s4  = wsrc[ 4*BLK + t]; s5  = wsrc[ 5*BLK + t];
        s6  = wsrc[ 6*BLK + t]; s7  = wsrc[ 7*BLK + t];
        s8  = wsrc[ 8*BLK + t]; s9  = wsrc[ 9*BLK + t];
        s10 = wsrc[10*BLK + t]; s11 = wsrc[11*BLK + t];
        s12 = wsrc[12*BLK + t]; s13 = wsrc[13*BLK + t];
        s14 = wsrc[14*BLK + t]; s15 = wsrc[15*BLK + t];
    }
    __syncthreads();                               // barrier 2: patch reads done
    {
        uint4* wdst = (uint4*)uLDS;
        wdst[ 0*BLK + t] = s0;  wdst[ 1*BLK + t] = s1;
        wdst[ 2*BLK + t] = s2;  wdst[ 3*BLK + t] = s3;
        wdst[ 4*BLK + t] = s4;  wdst[ 5*BLK + t] = s5;
        wdst[ 6*BLK + t] = s6;  wdst[ 7*BLK + t] = s7;
        wdst[ 8*BLK + t] = s8;  wdst[ 9*BLK + t] = s9;
        wdst[10*BLK + t] = s10; wdst[11*BLK + t] = s11;
        wdst[12*BLK + t] = s12; wdst[13*BLK + t] = s13;
        wdst[14*BLK + t] = s14; wdst[15*BLK + t] = s15;
    }
    __syncthreads();                               // barrier 3: wlS ready

    // ===== phase 3: all-leaf GEMM, B-frags from LDS; cndmask select =====
    f32x4 keep[4];
    #pragma unroll
    for (int rt = 0; rt < 4; ++rt) keep[rt] = (f32x4){0.f, 0.f, 0.f, 0.f};

    #pragma unroll 2
    for (int nt = 0; nt < NL; ++nt) {
        const short8v bf0 = *(const short8v*)&wlS[nt * 2048 + (0 * 64 + lane) * 8];
        const short8v bf1 = *(const short8v*)&wlS[nt * 2048 + (1 * 64 + lane) * 8];
        const short8v bf2 = *(const short8v*)&wlS[nt * 2048 + (2 * 64 + lane) * 8];
        const short8v bf3 = *(const short8v*)&wlS[nt * 2048 + (3 * 64 + lane) * 8];
        f32x4 acc[4];
        #pragma unroll
        for (int rt = 0; rt < 4; ++rt) acc[rt] = (f32x4){0.f, 0.f, 0.f, 0.f};
        #pragma unroll
        for (int rt = 0; rt < 4; ++rt) {
            acc[rt] = __builtin_amdgcn_mfma_f32_16x16x32_bf16(ah[0][rt], bf0, acc[rt], 0, 0, 0);
            acc[rt] = __builtin_amdgcn_mfma_f32_16x16x32_bf16(ah[1][rt], bf1, acc[rt], 0, 0, 0);
            acc[rt] = __builtin_amdgcn_mfma_f32_16x16x32_bf16(ah[2][rt], bf2, acc[rt], 0, 0, 0);
            acc[rt] = __builtin_amdgcn_mfma_f32_16x16x32_bf16(ah[3][rt], bf3, acc[rt], 0, 0, 0);
        }
        #pragma unroll
        for (int rt = 0; rt < 4; ++rt)
            #pragma unroll
            for (int j = 0; j < 4; ++j)
                keep[rt][j] = (((lfp[rt] >> (8 * j)) & 0xFFu) == (unsigned)nt)
                            ? acc[rt][j] : keep[rt][j];
    }

    // ===== epilogue: patch reuses wlS region after all B reads done =====
    __syncthreads();                               // barrier 4
    {
        float* p_ = &patch[wv * 64 * OSTR];
        #pragma unroll
        for (int rt = 0; rt < 4; ++rt)
            #pragma unroll
            for (int j = 0; j < 4; ++j) {
                const int lf = (lfp[rt] >> (8 * j)) & 0xFF;
                p_[(rt * 16 + grp * 4 + j) * OSTR + lo16] =
                    keep[rt][j] + sBl[lf * OC + lo16];
            }
    }
    asm volatile("s_waitcnt lgkmcnt(0)" ::: "memory");
    __builtin_amdgcn_sched_barrier(0);
    {
        const float* so = &patch[t * OSTR];        // own wave's rows: wave-private
        const float4 m0 = *(const float4*)(so);
        const float4 m1 = *(const float4*)(so + 4);
        const float4 q0 = *(const float4*)(so + 8);
        const float4 q1 = *(const float4*)(so + 12);

        const size_t ob = (size_t)(rowBase + t) * 8;
        *reinterpret_cast<float4*>(&out[ob])     = m0;
        *reinterpret_cast<float4*>(&out[ob + 4]) = m1;

        // log_std = -1.5 + 3.5*tanh(v); tanh = 1 - 2/(e^{2v}+1)
        float4 r0, r1;
        #define SQ(v) (-1.5f + 3.5f * (1.f - 2.f / (__expf(2.f * (v)) + 1.f)))
        r0.x = SQ(q0.x); r0.y = SQ(q0.y); r0.z = SQ(q0.z); r0.w = SQ(q0.w);
        r1.x = SQ(q1.x); r1.y = SQ(q1.y); r1.z = SQ(q1.z); r1.w = SQ(q1.w);
        #undef SQ
        const size_t ob2 = (size_t)B * 8 + ob;
        *reinterpret_cast<float4*>(&out[ob2])     = r0;
        *reinterpret_cast<float4*>(&out[ob2 + 4]) = r1;
    }
}

extern "C" void kernel_launch(void* const* d_in, const int* in_sizes, int n_in,
                              void* d_out, int out_size, void* d_ws, size_t ws_size,
                              hipStream_t stream)
{
    const float* x  = (const float*)d_in[0];
    const float* Wn = (const float*)d_in[1];
    const float* bn = (const float*)d_in[2];
    const float* Wl = (const float*)d_in[3];
    const float* bl = (const float*)d_in[4];
    float* out = (float*)d_out;

    unsigned short* wlB  = (unsigned short*)d_ws;          // 32768 bf16
    unsigned short* wnHi = wlB + 32768;                    //  2048 bf16
    unsigned short* wnLo = wnHi + 2048;                    //  2048 bf16

    const int B = in_sizes[0] / DD;              // 262144
    const int blocks = (B + BLK - 1) / BLK;      // 1024

    hipLaunchKernelGGL(dts_prep, dim3(136), dim3(256), 0, stream, Wn, Wl, wlB, wnHi, wnLo);
    hipLaunchKernelGGL(dts_fused17, dim3(blocks), dim3(BLK), 0, stream,
                       x, Wn, bn, bl, wlB, wnHi, wnLo, out, B);
}